// Round 5
// baseline (213.030 us; speedup 1.0000x reference)
//
#include <hip/hip_runtime.h>
#include <hip/hip_cooperative_groups.h>
#include <cstdint>

namespace cg = cooperative_groups;
typedef unsigned long long ull;

#define N_BOX 8192
#define N_WORDS 128   // 8192 / 64
#define CH 512        // chunk size
#define WPC 8         // words per chunk
#define NBLK 256      // grid (1 block/CU; <=2/CU co-resident so coop launch is legal)

// ---------------- workspace layout ----------------
// TB (triangular transposed col-blocks): 61440 rows * 64 B = 3,932,160 @ 0
// TD (per-chunk transposed tables):      16 * 32 KB        =   524,288 @ 3,932,160
// boxes4  : 131072 B @ 4,456,448
// scores  : 32768  B @ 4,587,520
// partials: 1024   B @ 4,620,288
// mask    : 1024   B @ 4,653,056
// vb      : 4 B      @ 4,654,084
#define OFF_TB     0
#define OFF_TD     3932160
#define OFF_BOXES  4456448
#define OFF_SCORES 4587520
#define OFF_PART   4620288
#define OFF_MASK   4653056
#define OFF_VB     4654084

// rows before chunk c in TB = sum_{c'<c} (8192 - 512*(c'+1))
__device__ __forceinline__ int rows_before(int c) {
    return 8192 * c - 256 * c * (c + 1);
}

__device__ __forceinline__ ull make_key(float s, int idx) {
    // positive floats: bit pattern is order-preserving. Reversed index in the
    // low 13 bits reproduces stable argsort(-conf): equal conf -> lower index first.
    return (((ull)__float_as_uint(s)) << 13) | (ull)(8191 - idx);
}

__device__ __forceinline__ float box_area(float4 b) {
    return __fmul_rn(__fsub_rn(b.z, b.x), __fsub_rn(b.w, b.y));
}

// exact replica of reference IoU rounding (_rn ops block FMA contraction); symmetric.
__device__ __forceinline__ bool iou_gt_half(float4 a, float aarea, float4 b, float barea) {
    float ix1 = fmaxf(a.x, b.x);
    float iy1 = fmaxf(a.y, b.y);
    float ix2 = fminf(a.z, b.z);
    float iy2 = fminf(a.w, b.w);
    float iw = fmaxf(__fsub_rn(ix2, ix1), 0.0f);
    float ih = fmaxf(__fsub_rn(iy2, iy1), 0.0f);
    float inter = __fmul_rn(iw, ih);
    float uni = __fsub_rn(__fadd_rn(aarea, barea), inter);
    float iou = __fdiv_rn(inter, fmaxf(uni, 1e-9f));
    return iou > 0.5f;
}

struct SMemB { ull keys[N_BOX]; };                 // 64 KB (phase B)
struct SMemD { float4 sb[CH]; float sa[CH]; };     // 10 KB (phase D)
struct SMemE { ull TDb[2][CH * WPC]; };            // 64 KB (phase E)
union SMemU { SMemB b; SMemD d; SMemE e; };

__global__ __launch_bounds__(1024, 4) void fused_nms(
        const float* __restrict__ in,
        ull* __restrict__ TB, ull* __restrict__ TD,
        float4* __restrict__ boxes4, float* __restrict__ scores,
        float* __restrict__ partials, ull* __restrict__ maskg,
        int* __restrict__ vbp, float* __restrict__ out)
{
    __shared__ SMemU sm;
    __shared__ unsigned amask32[2 * N_WORDS];
    __shared__ ull keptw[WPC];
    __shared__ float smax;
    __shared__ int rnk[32];
    __shared__ int svb;
    cg::grid_group grid = cg::this_grid();
    int bid = blockIdx.x;
    int t = threadIdx.x;
    int lane = t & 63;
    int wave = t >> 6;

    // ---------- Phase A: per-block partial max of conf; zero mask/vb ----------
    if (t < 32) {
        float c = in[(bid * 32 + t) * 5 + 4];   // conf >= 0
        for (int off = 16; off; off >>= 1) c = fmaxf(c, __shfl_down(c, off));
        if (t == 0) partials[bid] = c;
    }
    if (bid == 0) {
        if (t < N_WORDS) maskg[t] = 0ull;
        if (t == 0) *vbp = 0;
    }
    grid.sync();

    // ---------- Phase B: global max + keys in LDS + exact ranks for my 32 boxes ----------
    if (t < 64) {
        float m = fmaxf(fmaxf(partials[t], partials[t + 64]),
                        fmaxf(partials[t + 128], partials[t + 192]));
        for (int off = 32; off; off >>= 1) m = fmaxf(m, __shfl_down(m, off));
        if (t == 0) smax = m;
    }
    if (t < 32) rnk[t] = 0;
    __syncthreads();
    float maxc = smax;
    #pragma unroll
    for (int r = 0; r < 8; ++r) {
        int j = r * 1024 + t;
        sm.b.keys[j] = make_key(__fdiv_rn(in[j * 5 + 4], maxc), j);
    }
    __syncthreads();
    {
        int i = bid * 32 + (t & 31);
        ull ki = sm.b.keys[i];
        int slice = t >> 5;                 // 32 slices of 256 j each
        int cnt = 0;
        #pragma unroll 8
        for (int k = 0; k < 256; ++k) cnt += (sm.b.keys[slice * 256 + k] > ki) ? 1 : 0;
        atomicAdd(&rnk[t & 31], cnt);
    }
    __syncthreads();

    // ---------- Phase C: scatter into sorted order + valid mask ----------
    if (t < 32) {
        int ii = bid * 32 + t;
        float cx = in[ii * 5 + 0];
        float cy = in[ii * 5 + 1];
        float w  = in[ii * 5 + 2];
        float h  = in[ii * 5 + 3];
        float s  = __fdiv_rn(in[ii * 5 + 4], maxc);
        int r = rnk[t];
        float4 b;
        b.x = __fsub_rn(cx, __fmul_rn(w, 0.5f));
        b.y = __fsub_rn(cy, __fmul_rn(h, 0.5f));
        b.z = __fadd_rn(cx, __fmul_rn(w, 0.5f));
        b.w = __fadd_rn(cy, __fmul_rn(h, 0.5f));
        boxes4[r] = b;
        scores[r] = s;
        if (s >= 0.5f) {
            atomicOr(&maskg[r >> 6], 1ull << (r & 63));
            atomicAdd(vbp, 1);
        }
    }
    grid.sync();

    // ---------- Phase D: build TB + TD (grid-stride over 544 virtual tiles) ----------
    // vt < 64: TD tile (chunk c = vt>>2, row-tile vt&3, 128 rows).
    // vt >= 64: TB tile; chunk c has 60-4c tiles of 128 rows.
    for (int vt = bid; vt < 544; vt += NBLK) {
        int c, jt;
        bool diag;
        if (vt < 64) { diag = true; c = vt >> 2; jt = vt & 3; }
        else {
            diag = false;
            int id = vt - 64;
            c = 0;
            while (id >= 60 - 4 * c) { id -= 60 - 4 * c; ++c; }
            jt = id;
        }
        bool active = (scores[c * CH] >= 0.5f);      // block-uniform gating
        int j0 = diag ? (jt * 128) : (CH * (c + 1) + jt * 128);
        if (active && !diag) active = (scores[j0] >= 0.5f);
        if (active) {
            __syncthreads();
            if (t < CH) {
                float4 b = boxes4[c * CH + t];
                sm.d.sb[t] = b;
                sm.d.sa[t] = box_area(b);
            }
            __syncthreads();
            int r = t >> 3;
            int w = t & 7;
            if (diag) {
                int jl = j0 + r;
                float4 me = sm.d.sb[jl];
                float ma = sm.d.sa[jl];
                int wj = jl >> 6;
                int lim = (w < wj) ? 64 : ((w == wj) ? (jl & 63) : 0);
                ull bits = 0;
                for (int k = 0; k < lim; ++k)
                    if (iou_gt_half(sm.d.sb[w * 64 + k], sm.d.sa[w * 64 + k], me, ma))
                        bits |= 1ull << k;
                TD[c * 4096 + w * 512 + jl] = bits;
            } else {
                int j = j0 + r;
                float4 me = boxes4[j];
                float ma = box_area(me);
                ull bits = 0;
                for (int k = 0; k < 64; ++k)
                    if (iou_gt_half(sm.d.sb[w * 64 + k], sm.d.sa[w * 64 + k], me, ma))
                        bits |= 1ull << k;
                TB[(size_t)(rows_before(c) + (j - CH * (c + 1))) * WPC + w] = bits;
            }
        }
    }
    grid.sync();

    // ---------- Phase E: block 0 runs the serial NMS (R4 k5 verbatim) ----------
    if (bid != 0) return;

    if (t < 2 * N_WORDS) amask32[t] = ((const unsigned*)maskg)[t];
    if (t == 0) svb = *vbp;
    if (t < WPC) keptw[t] = 0;
    for (int i2 = t; i2 < CH * WPC; i2 += 1024) sm.e.TDb[0][i2] = TD[i2];   // chunk 0
    __syncthreads();

    int vb = svb;
    int nchv = (vb + CH - 1) / CH;
    int cur = 0;
    for (int c = 0; c < nchv; ++c) {
        if (wave == 0) {
            const ull* T = sm.e.TDb[cur];
            ull alive[WPC];
            #pragma unroll
            for (int w = 0; w < WPC; ++w)
                alive[w] = (ull)amask32[c * 16 + 2 * w] |
                           ((ull)amask32[c * 16 + 2 * w + 1] << 32);
            #pragma unroll
            for (int w = 0; w < WPC; ++w) {
                ull word = alive[w];
                if (!word) continue;
                ull td = T[w * 512 + w * 64 + lane];   // intra-word suppressors of my lane
                ull a2 = word, kept = 0;
                while (a2 & ~kept) {
                    bool al = (a2 >> lane) & 1;
                    bool kp = (kept >> lane) & 1;
                    ull nk = __ballot(al && !kp && ((td & a2) == 0));
                    ull nd = __ballot(al && !kp && ((td & kept) != 0));
                    kept |= nk;
                    a2 &= ~nd;
                }
                alive[w] = kept;
                #pragma unroll
                for (int j = 0; j < WPC; ++j) {
                    if (j <= w) continue;
                    if (!alive[j]) continue;
                    ull m = T[w * 512 + j * 64 + lane];
                    alive[j] &= ~__ballot((m & kept) != 0);
                }
            }
            if (lane == 0) {
                #pragma unroll
                for (int w = 0; w < WPC; ++w) {
                    amask32[c * 16 + 2 * w]     = (unsigned)alive[w];
                    amask32[c * 16 + 2 * w + 1] = (unsigned)(alive[w] >> 32);
                    keptw[w] = alive[w];
                }
            }
        } else if (c + 1 < nchv) {
            int base = (c + 1) * CH * WPC;
            for (int i2 = t - 64; i2 < CH * WPC; i2 += 960)
                sm.e.TDb[cur ^ 1][i2] = TD[base + i2];
        }
        __syncthreads();

        ull kw[WPC];
        ull anyk = 0;
        #pragma unroll
        for (int k = 0; k < WPC; ++k) { kw[k] = keptw[k]; anyk |= kw[k]; }
        if (anyk) {
            const ull* TBc = TB + (size_t)rows_before(c) * WPC;
            int jbase = CH * (c + 1);
            for (int j = jbase + t; j < vb; j += 1024) {
                if ((amask32[j >> 5] >> (j & 31)) & 1u) {
                    const ull* r = TBc + (size_t)(j - jbase) * WPC;
                    ull acc = 0;
                    #pragma unroll
                    for (int k = 0; k < WPC; ++k) acc |= r[k] & kw[k];
                    if (acc) atomicAnd(&amask32[j >> 5], ~(1u << (j & 31)));
                }
            }
        }
        cur ^= 1;
        __syncthreads();
    }

    // ---------- epilogue: write all 8192 output rows ----------
    #pragma unroll
    for (int rr = 0; rr < 8; ++rr) {
        int j = t * 8 + rr;
        bool kept = (amask32[j >> 5] >> (j & 31)) & 1u;
        float4 b = boxes4[j];
        float s = scores[j];
        out[j * 5 + 0] = kept ? b.x : 0.0f;
        out[j * 5 + 1] = kept ? b.y : 0.0f;
        out[j * 5 + 2] = kept ? b.z : 0.0f;
        out[j * 5 + 3] = kept ? b.w : 0.0f;
        out[j * 5 + 4] = kept ? s   : 0.0f;
    }
}

extern "C" void kernel_launch(void* const* d_in, const int* in_sizes, int n_in,
                              void* d_out, int out_size, void* d_ws, size_t ws_size,
                              hipStream_t stream) {
    const float* in = (const float*)d_in[0];
    char* ws = (char*)d_ws;
    ull* TB        = (ull*)(ws + OFF_TB);
    ull* TD        = (ull*)(ws + OFF_TD);
    float4* boxes4 = (float4*)(ws + OFF_BOXES);
    float* scores  = (float*)(ws + OFF_SCORES);
    float* partials= (float*)(ws + OFF_PART);
    ull* maskg     = (ull*)(ws + OFF_MASK);
    int* vbp       = (int*)(ws + OFF_VB);
    float* out     = (float*)d_out;

    void* args[] = { (void*)&in, (void*)&TB, (void*)&TD, (void*)&boxes4,
                     (void*)&scores, (void*)&partials, (void*)&maskg,
                     (void*)&vbp, (void*)&out };
    hipLaunchCooperativeKernel(reinterpret_cast<void*>(fused_nms),
                               dim3(NBLK), dim3(1024), args, 0, stream);
}